// Round 5
// baseline (2272.434 us; speedup 1.0000x reference)
//
#include <hip/hip_runtime.h>
#include <hip/hip_bf16.h>
#include <math.h>

typedef __hip_bfloat16 bf16;
typedef __attribute__((ext_vector_type(8))) short short8;
typedef __attribute__((ext_vector_type(4))) float f32x4;

// ---------- epilogue ids ----------
enum {
    M_H2 = 0,   // relu(acc + bias[gn]) -> split (sO)
    M_V,        // tanh(acc + bias[gn]) * ub[gn&7] -> split (Nreal 400, pad 416)
    M_KM,       // acc + 2*(m==n) -> split + fp32 Km[400x400]
    M_W,        // acc -> split
    M_NS,       // 2*Xf - acc -> split + fp32 Xf'
    M_FK,       // acc -> split + transposed split
    M_G,        // acc -> split (832)
    M_C2,       // 2*acc -> fp32 (gn<800)
    M_ZI,       // z=min(acc,Bb); yv=0 -> split z (stride sO=832)
    M_U1,       // acc -> fp32 U1 (gn<400)
    M_FIN,      // 2*acc + U1 -> out[gn*1024+gm] (gn<400), dtype per flag
    M_BB,       // acc + g[gn] -> fp32 Bb (gn<800)
};

__device__ __forceinline__ float ldf(const void* p, long i, int f32) {
    return f32 ? ((const float*)p)[i]
               : __bfloat162float(((const bf16*)p)[i]);
}
__device__ __forceinline__ void split_bf16(float z, short& hi, short& lo) {
    bf16 h = __float2bfloat16(z);
    hi = *reinterpret_cast<short*>(&h);
    bf16 l = __float2bfloat16(z - __bfloat162float(h));
    lo = *reinterpret_cast<short*>(&l);
}
__device__ __forceinline__ void sstore(short* H, short* L, long o, float v) {
    short h, l; split_bf16(v, h, l); H[o] = h; L[o] = l;
}

// ---------- dtype detect (+ zero the rowmax scalar) ----------
__global__ void detect_kernel(const void* Fp, int* flag, int* sc) {
    __shared__ int hit;
    if (threadIdx.x == 0) { hit = 0; sc[0] = 0; }
    __syncthreads();
    const unsigned short* u = (const unsigned short*)Fp;
    int local = 0;
    for (int i = threadIdx.x; i < 16384; i += 256) {
        int e = (u[i] >> 7) & 0xFF;
        if (e >= 0x90) local = 1;
    }
    if (local) atomicOr(&hit, 1);
    __syncthreads();
    if (threadIdx.x == 0) flag[0] = hit;
}

// ---------- fused input prep: transpose/pad + split everything ----------
__global__ __launch_bounds__(256)
void prep_kernel(const void* __restrict__ F, const void* __restrict__ W2,
                 const void* __restrict__ W3, const void* __restrict__ X0,
                 const void* __restrict__ W1, const void* __restrict__ H0,
                 short* __restrict__ Fth, short* __restrict__ Ftl,
                 short* __restrict__ Fsh, short* __restrict__ Fsl,
                 short* __restrict__ W2h, short* __restrict__ W2l,
                 short* __restrict__ W3h, short* __restrict__ W3l,
                 short* __restrict__ X0h, short* __restrict__ X0l,
                 short* __restrict__ W1h, short* __restrict__ W1l,
                 short* __restrict__ H0h, short* __restrict__ H0l,
                 const int* __restrict__ flag)
{
    const int f32 = flag[0];
    int idx = blockIdx.x * 256 + threadIdx.x;
    // F [800x400]: Ft[j*800+i] and Fs[i*416+j]
    if (idx < 320000) {
        int i = idx / 400, j = idx % 400;
        float v = ldf(F, idx, f32);
        sstore(Fth, Ftl, (long)j * 800 + i, v);
        sstore(Fsh, Fsl, (long)i * 416 + j, v);
        return;
    }
    idx -= 320000;
    // W2 [512x512]: W2t[n*512+k]
    if (idx < 262144) {
        int k = idx >> 9, n = idx & 511;
        sstore(W2h, W2l, (long)n * 512 + k, ldf(W2, idx, f32));
        return;
    }
    idx -= 262144;
    // W3 [512x400]: W3t[n*512+k]
    if (idx < 204800) {
        int k = idx / 400, n = idx % 400;
        sstore(W3h, W3l, (long)n * 512 + k, ldf(W3, idx, f32));
        return;
    }
    idx -= 204800;
    // X0 [32x1024]: X0t[b*32+k]
    if (idx < 32768) {
        int k = idx >> 10, b = idx & 1023;
        sstore(X0h, X0l, (long)b * 32 + k, ldf(X0, idx, f32));
        return;
    }
    idx -= 32768;
    // W1 [32x512]: W1t[n*32+k]
    if (idx < 16384) {
        int k = idx >> 9, n = idx & 511;
        sstore(W1h, W1l, (long)n * 32 + k, ldf(W1, idx, f32));
        return;
    }
    idx -= 16384;
    // H0 [800x32]: direct copy-split
    if (idx < 25600) {
        sstore(H0h, H0l, idx, ldf(H0, idx, f32));
    }
}

// ---------- generic split-3 MFMA GEMM, 64x64 tile, BK=32, reg-prefetch ----------
template<int EPI>
__global__ __launch_bounds__(256)
void mgemm(const short* __restrict__ Ah, const short* __restrict__ Al, int sA,
           const short* __restrict__ Bth, const short* __restrict__ Btl, int sB,
           int KC,
           short* __restrict__ Oh, short* __restrict__ Ol, int sO,
           short* __restrict__ Oth, short* __restrict__ Otl,
           float* __restrict__ fout, const float* __restrict__ faux,
           const void* __restrict__ bias, const void* __restrict__ ubp,
           void* __restrict__ rawout, const int* __restrict__ flag)
{
    __shared__ __align__(16) short Ahs[64][32];
    __shared__ __align__(16) short Als[64][32];
    __shared__ __align__(16) short Bhs[64][32];
    __shared__ __align__(16) short Bls[64][32];

    const int tid = threadIdx.x;
    const int m0 = blockIdx.x * 64, n0 = blockIdx.y * 64;
    const int wave = tid >> 6, lane = tid & 63;
    const int wm = (wave & 1) * 32, wn = (wave >> 1) * 32;
    const int q = lane >> 4, r = lane & 15;
    const int sm = tid >> 2, sk = (tid & 3) * 8;

    f32x4 acc[2][2];
#pragma unroll
    for (int t = 0; t < 2; t++)
#pragma unroll
        for (int u = 0; u < 2; u++)
#pragma unroll
            for (int i = 0; i < 4; i++) acc[t][u][i] = 0.f;

    const long arow = (long)(m0 + sm) * sA + sk;
    const long brow = (long)(n0 + sm) * sB + sk;

    uint4 pAh = *(const uint4*)&Ah[arow];
    uint4 pAl = *(const uint4*)&Al[arow];
    uint4 pBh = *(const uint4*)&Bth[brow];
    uint4 pBl = *(const uint4*)&Btl[brow];

    for (int c = 0; c < KC; c++) {
        __syncthreads();
        *(uint4*)&Ahs[sm][sk] = pAh;
        *(uint4*)&Als[sm][sk] = pAl;
        *(uint4*)&Bhs[sm][sk] = pBh;
        *(uint4*)&Bls[sm][sk] = pBl;
        if (c + 1 < KC) {
            int k0 = (c + 1) * 32;
            pAh = *(const uint4*)&Ah[arow + k0];
            pAl = *(const uint4*)&Al[arow + k0];
            pBh = *(const uint4*)&Bth[brow + k0];
            pBl = *(const uint4*)&Btl[brow + k0];
        }
        __syncthreads();

        short8 a_h[2], a_l[2], b_h[2], b_l[2];
#pragma unroll
        for (int t = 0; t < 2; t++) {
            a_h[t] = *(const short8*)&Ahs[wm + t * 16 + r][q * 8];
            a_l[t] = *(const short8*)&Als[wm + t * 16 + r][q * 8];
        }
#pragma unroll
        for (int u = 0; u < 2; u++) {
            b_h[u] = *(const short8*)&Bhs[wn + u * 16 + r][q * 8];
            b_l[u] = *(const short8*)&Bls[wn + u * 16 + r][q * 8];
        }
#pragma unroll
        for (int t = 0; t < 2; t++)
#pragma unroll
            for (int u = 0; u < 2; u++) {
                acc[t][u] = __builtin_amdgcn_mfma_f32_16x16x32_bf16(a_h[t], b_h[u], acc[t][u], 0, 0, 0);
                acc[t][u] = __builtin_amdgcn_mfma_f32_16x16x32_bf16(a_h[t], b_l[u], acc[t][u], 0, 0, 0);
                acc[t][u] = __builtin_amdgcn_mfma_f32_16x16x32_bf16(a_l[t], b_h[u], acc[t][u], 0, 0, 0);
            }
    }

    const int f32 = flag[0];
    // C/D layout: col = lane&15 (gn), row = quad*4 + reg (gm)
#pragma unroll
    for (int t = 0; t < 2; t++) {
#pragma unroll
        for (int u = 0; u < 2; u++) {
            int gn = n0 + wn + u * 16 + r;
#pragma unroll
            for (int i = 0; i < 4; i++) {
                int gm = m0 + wm + t * 16 + q * 4 + i;
                float v = acc[t][u][i];
                if constexpr (EPI == M_H2) {
                    float val = fmaxf(v + ldf(bias, gn, f32), 0.f);
                    sstore(Oh, Ol, (long)gm * sO + gn, val);
                } else if constexpr (EPI == M_V) {
                    if (gn < 416) {
                        float val = 0.f;
                        if (gn < 400)
                            val = tanhf(v + ldf(bias, gn, f32)) * ldf(ubp, gn & 7, f32);
                        sstore(Oh, Ol, (long)gm * sO + gn, val);
                    }
                } else if constexpr (EPI == M_KM) {
                    if (gn < 416) {
                        float val = 0.f;
                        if (gm < 400 && gn < 400) {
                            val = v + ((gm == gn) ? 2.f : 0.f);
                            fout[gm * 400 + gn] = val;
                        }
                        sstore(Oh, Ol, (long)gm * sO + gn, val);
                    }
                } else if constexpr (EPI == M_W) {
                    if (gn < 416) sstore(Oh, Ol, (long)gm * sO + gn, v);
                } else if constexpr (EPI == M_NS) {
                    if (gn < 416) {
                        float val = 0.f;
                        if (gm < 400 && gn < 400) {
                            val = 2.f * faux[gm * 400 + gn] - v;
                            fout[gm * 400 + gn] = val;
                        }
                        sstore(Oh, Ol, (long)gm * sO + gn, val);
                    }
                } else if constexpr (EPI == M_FK) {
                    if (gn < 416) sstore(Oh, Ol, (long)gm * sO + gn, v);
                    if (gm < 800) sstore(Oth, Otl, (long)gn * 800 + gm, v);
                } else if constexpr (EPI == M_G) {
                    sstore(Oh, Ol, (long)gm * sO + gn, v);
                } else if constexpr (EPI == M_C2) {
                    if (gn < 800) fout[(long)gm * 800 + gn] = 2.f * v;
                } else if constexpr (EPI == M_ZI) {
                    if (gn < 800) {
                        long o8 = (long)gm * 800 + gn;
                        float z = fminf(v, faux[o8]);
                        fout[o8] = 0.f;   // yv = 0
                        sstore(Oh, Ol, (long)gm * sO + gn, z);
                    }
                } else if constexpr (EPI == M_U1) {
                    if (gn < 400) fout[(long)gm * 400 + gn] = v;
                } else if constexpr (EPI == M_FIN) {
                    if (gn < 400) {
                        float val = 2.f * v + faux[(long)gm * 400 + gn];
                        long oo = (long)gn * 1024 + gm;
                        if (f32) ((float*)rawout)[oo] = val;
                        else     ((bf16*)rawout)[oo] = __float2bfloat16(val);
                    }
                } else if constexpr (EPI == M_BB) {
                    if (gn < 800) fout[(long)gm * 800 + gn] = v + ldf(bias, gn, f32);
                }
            }
        }
    }
}

// ---------- ADMM iteration: BK=64 (2 ksubs), reg-prefetch, z stride 832 ----------
__global__ __launch_bounds__(256)
void admm_mfma(const short* __restrict__ zhi, const short* __restrict__ zlo,
               const short* __restrict__ Ghi, const short* __restrict__ Glo,
               const float* __restrict__ C2, float* __restrict__ yv,
               const float* __restrict__ Bb,
               short* __restrict__ zhi_o, short* __restrict__ zlo_o)
{
    __shared__ __align__(16) short Ahs[2][64][32];
    __shared__ __align__(16) short Als[2][64][32];
    __shared__ __align__(16) short Bhs[2][64][32];
    __shared__ __align__(16) short Bls[2][64][32];

    const int tid = threadIdx.x;
    const int m0 = blockIdx.x * 64, n0 = blockIdx.y * 64;
    const int wave = tid >> 6, lane = tid & 63;
    const int wm = (wave & 1) * 32, wn = (wave >> 1) * 32;
    const int q = lane >> 4, r = lane & 15;
    const int row = tid >> 2, col8 = (tid & 3) * 8;

    f32x4 acc[2][2];
#pragma unroll
    for (int t = 0; t < 2; t++)
#pragma unroll
        for (int u = 0; u < 2; u++)
#pragma unroll
            for (int i = 0; i < 4; i++) acc[t][u][i] = 0.f;

    const long abase = (long)(m0 + row) * 832 + col8;
    const long bbase = (long)(n0 + row) * 832 + col8;

    uint4 pAh[2], pAl[2], pBh[2], pBl[2];
#pragma unroll
    for (int s = 0; s < 2; s++) {
        pAh[s] = *(const uint4*)&zhi[abase + s * 32];
        pAl[s] = *(const uint4*)&zlo[abase + s * 32];
        pBh[s] = *(const uint4*)&Ghi[bbase + s * 32];
        pBl[s] = *(const uint4*)&Glo[bbase + s * 32];
    }

    for (int c = 0; c < 13; c++) {
        __syncthreads();
#pragma unroll
        for (int s = 0; s < 2; s++) {
            *(uint4*)&Ahs[s][row][col8] = pAh[s];
            *(uint4*)&Als[s][row][col8] = pAl[s];
            *(uint4*)&Bhs[s][row][col8] = pBh[s];
            *(uint4*)&Bls[s][row][col8] = pBl[s];
        }
        if (c < 12) {
            long ka = abase + (long)(c + 1) * 64;
            long kb = bbase + (long)(c + 1) * 64;
#pragma unroll
            for (int s = 0; s < 2; s++) {
                pAh[s] = *(const uint4*)&zhi[ka + s * 32];
                pAl[s] = *(const uint4*)&zlo[ka + s * 32];
                pBh[s] = *(const uint4*)&Ghi[kb + s * 32];
                pBl[s] = *(const uint4*)&Glo[kb + s * 32];
            }
        }
        __syncthreads();

#pragma unroll
        for (int s = 0; s < 2; s++) {
            short8 a_h[2], a_l[2], b_h[2], b_l[2];
#pragma unroll
            for (int t = 0; t < 2; t++) {
                a_h[t] = *(const short8*)&Ahs[s][wm + t * 16 + r][q * 8];
                a_l[t] = *(const short8*)&Als[s][wm + t * 16 + r][q * 8];
            }
#pragma unroll
            for (int u = 0; u < 2; u++) {
                b_h[u] = *(const short8*)&Bhs[s][wn + u * 16 + r][q * 8];
                b_l[u] = *(const short8*)&Bls[s][wn + u * 16 + r][q * 8];
            }
#pragma unroll
            for (int t = 0; t < 2; t++)
#pragma unroll
                for (int u = 0; u < 2; u++) {
                    acc[t][u] = __builtin_amdgcn_mfma_f32_16x16x32_bf16(a_h[t], b_h[u], acc[t][u], 0, 0, 0);
                    acc[t][u] = __builtin_amdgcn_mfma_f32_16x16x32_bf16(a_h[t], b_l[u], acc[t][u], 0, 0, 0);
                    acc[t][u] = __builtin_amdgcn_mfma_f32_16x16x32_bf16(a_l[t], b_h[u], acc[t][u], 0, 0, 0);
                }
        }
    }

#pragma unroll
    for (int t = 0; t < 2; t++) {
#pragma unroll
        for (int u = 0; u < 2; u++) {
            int gn = n0 + wn + u * 16 + r;
            if (gn >= 800) continue;
#pragma unroll
            for (int i = 0; i < 4; i++) {
                int gm = m0 + wm + t * 16 + q * 4 + i;
                long o8 = (long)gm * 800 + gn;
                float s = acc[t][u][i] + C2[o8] + yv[o8];
                float b = Bb[o8];
                float d = s - b;
                yv[o8] = fmaxf(d, 0.f);
                sstore(zhi_o, zlo_o, (long)gm * 832 + gn, b - fabsf(d));
            }
        }
    }
}

// ---------- Gershgorin bound: S = max_i sum_j |Km[i][j]| (atomicMax on int bits) ----------
__global__ __launch_bounds__(256)
void rowinf_kernel(const float* __restrict__ Km, int* __restrict__ s)
{
    int row = blockIdx.x * 4 + (threadIdx.x >> 6);
    int lane = threadIdx.x & 63;
    float sum = 0.f;
    for (int j = lane; j < 400; j += 64) sum += fabsf(Km[row * 400 + j]);
#pragma unroll
    for (int off = 32; off > 0; off >>= 1) sum += __shfl_down(sum, off, 64);
    if (lane == 0) atomicMax(s, __float_as_int(sum));
}

// X = t*I (fp32 + split), t = 2/(2 + S); valid since eig(K) in [2, S]
__global__ __launch_bounds__(256)
void xinit_kernel(float* __restrict__ Xf, short* __restrict__ Xh, short* __restrict__ Xl,
                  const int* __restrict__ s)
{
    int idx = blockIdx.x * 256 + threadIdx.x;
    if (idx >= 400 * 400) return;
    int i = idx / 400, j = idx % 400;
    float S = __int_as_float(s[0]);
    float t = 2.f / (2.f + S);
    float v = (i == j) ? t : 0.f;
    Xf[idx] = v;
    sstore(Xh, Xl, (long)i * 416 + j, v);
}

extern "C" void kernel_launch(void* const* d_in, const int* in_sizes, int n_in,
                              void* d_out, int out_size, void* d_ws, size_t ws_size,
                              hipStream_t stream)
{
    const void* X0 = d_in[0];
    const void* W1 = d_in[1];
    const void* b1 = d_in[2];
    const void* W2 = d_in[3];
    const void* b2 = d_in[4];
    const void* W3 = d_in[5];
    const void* b3 = d_in[6];
    const void* ub = d_in[7];
    const void* F  = d_in[8];
    const void* g  = d_in[9];
    const void* H0 = d_in[10];
    (void)in_sizes; (void)n_in; (void)out_size; (void)ws_size;

    char* w = (char*)d_ws;
    size_t off = 0;
    auto allocb = [&](size_t bytes) { char* p = w + off; off += (bytes + 15) & ~size_t(15); return p; };

    // fp32 region (fully overwritten before use every call)
    float* Km  = (float*)allocb(400 * 400 * 4);
    float* XfA = (float*)allocb(400 * 400 * 4);
    float* XfB = (float*)allocb(400 * 400 * 4);
    float* Bb  = (float*)allocb(1024 * 800 * 4);
    float* C2  = (float*)allocb(1024 * 800 * 4);
    float* yv  = (float*)allocb(1024 * 800 * 4);
    float* U1  = (float*)allocb(1024 * 400 * 4);
    int*   sc  = (int*)allocb(64);
    int*  flag = (int*)allocb(64);

    // split region (memset once per call -> zero rims)
    char* split_base = w + off;
    auto allocs = [&](size_t n) { return (short*)allocb(n * 2); };
    short *W1t_h = allocs(512*32),  *W1t_l = allocs(512*32);
    short *W2t_h = allocs(512*512), *W2t_l = allocs(512*512);
    short *W3t_h = allocs(448*512), *W3t_l = allocs(448*512);
    short *X0t_h = allocs(1024*32), *X0t_l = allocs(1024*32);
    short *H0s_h = allocs(832*32),  *H0s_l = allocs(832*32);
    short *H1h = allocs(1024*512),  *H1l = allocs(1024*512);
    short *H2h = allocs(1024*512),  *H2l = allocs(1024*512);
    short *Vh  = allocs(1024*416),  *Vl  = allocs(1024*416);
    short *Fsh = allocs(832*416),   *Fsl = allocs(832*416);
    short *Fth = allocs(448*800),   *Ftl = allocs(448*800);
    short *Kmh = allocs(448*416),   *Kml = allocs(448*416);
    short *XAh = allocs(448*416),   *XAl = allocs(448*416);
    short *XBh = allocs(448*416),   *XBl = allocs(448*416);
    short *Wsh = allocs(448*416),   *Wsl = allocs(448*416);
    short *FKh = allocs(832*416),   *FKl = allocs(832*416);
    short *FTh = allocs(448*800),   *FTl = allocs(448*800);
    short *Gh  = allocs(832*832),   *Gl  = allocs(832*832);
    short *zAh = allocs(1024*832),  *zAl = allocs(1024*832);
    short *zBh = allocs(1024*832),  *zBl = allocs(1024*832);
    size_t split_bytes = (size_t)((w + off) - split_base);

    short* NSo = nullptr;
    float* NFo = nullptr;
    const float* NF = nullptr;
    const void* NV = nullptr;

    // ---- detect dtype (+zero scalar), zero rims, prep all operands ----
    detect_kernel<<<1, 256, 0, stream>>>(F, flag, sc);
    hipMemsetAsync(split_base, 0, split_bytes, stream);
    prep_kernel<<<(861696 + 255) / 256, 256, 0, stream>>>(
        F, W2, W3, X0, W1, H0,
        Fth, Ftl, Fsh, Fsl, W2t_h, W2t_l, W3t_h, W3t_l,
        X0t_h, X0t_l, W1t_h, W1t_l, H0s_h, H0s_l, flag);

    // ---- MLP head: H1 = relu(X0^T W1 + b1); H2 = relu(H1 W2 + b2); V = tanh(H2 W3 + b3)*ub ----
    mgemm<M_H2><<<dim3(16, 8), 256, 0, stream>>>(X0t_h, X0t_l, 32, W1t_h, W1t_l, 32, 1,
        H1h, H1l, 512, NSo, NSo, NFo, NF, b1, NV, nullptr, flag);
    mgemm<M_H2><<<dim3(16, 8), 256, 0, stream>>>(H1h, H1l, 512, W2t_h, W2t_l, 512, 16,
        H2h, H2l, 512, NSo, NSo, NFo, NF, b2, NV, nullptr, flag);
    mgemm<M_V><<<dim3(16, 7), 256, 0, stream>>>(H2h, H2l, 512, W3t_h, W3t_l, 512, 16,
        Vh, Vl, 416, NSo, NSo, NFo, NF, b3, ub, nullptr, flag);

    // ---- Bb = g + X0^T H0^T  (M=1024,N=800,K=32) ----
    mgemm<M_BB><<<dim3(16, 13), 256, 0, stream>>>(X0t_h, X0t_l, 32, H0s_h, H0s_l, 32, 1,
        NSo, NSo, 0, NSo, NSo, Bb, NF, g, NV, nullptr, flag);

    // ---- Km = 2I + F^T F ----
    mgemm<M_KM><<<dim3(7, 7), 256, 0, stream>>>(Fth, Ftl, 800, Fth, Ftl, 800, 25,
        Kmh, Kml, 416, NSo, NSo, Km, NF, NV, NV, nullptr, flag);

    // ---- Kinv via Newton-Schulz, 8 iters; t from Gershgorin row-sum bound ----
    rowinf_kernel<<<100, 256, 0, stream>>>(Km, sc);
    xinit_kernel<<<625, 256, 0, stream>>>(XfA, XAh, XAl, sc);
    short *Xch = XAh, *Xcl = XAl, *Xnh = XBh, *Xnl = XBl;
    float *Xfc = XfA, *Xfn = XfB;
    for (int it = 0; it < 8; it++) {
        mgemm<M_W><<<dim3(7, 7), 256, 0, stream>>>(Xch, Xcl, 416, Kmh, Kml, 416, 13,
            Wsh, Wsl, 416, NSo, NSo, NFo, NF, NV, NV, nullptr, flag);
        mgemm<M_NS><<<dim3(7, 7), 256, 0, stream>>>(Wsh, Wsl, 416, Xch, Xcl, 416, 13,
            Xnh, Xnl, 416, NSo, NSo, Xfn, Xfc, NV, NV, nullptr, flag);
        short* t;
        t = Xch; Xch = Xnh; Xnh = t;
        t = Xcl; Xcl = Xnl; Xnl = t;
        float* tf = Xfc; Xfc = Xfn; Xfn = tf;
    }
    // (Xch,Xcl) == Kinv split (symmetric)

    // ---- FK = F@Kinv (+FK^T), C2 = 2V@FK^T, G = FK@F^T ----
    mgemm<M_FK><<<dim3(13, 7), 256, 0, stream>>>(Fsh, Fsl, 416, Xch, Xcl, 416, 13,
        FKh, FKl, 416, FTh, FTl, NFo, NF, NV, NV, nullptr, flag);
    mgemm<M_C2><<<dim3(16, 13), 256, 0, stream>>>(Vh, Vl, 416, FKh, FKl, 416, 13,
        NSo, NSo, 0, NSo, NSo, C2, NF, NV, NV, nullptr, flag);
    mgemm<M_G><<<dim3(13, 13), 256, 0, stream>>>(FKh, FKl, 416, Fsh, Fsl, 416, 13,
        Gh, Gl, 832, NSo, NSo, NFo, NF, NV, NV, nullptr, flag);

    // ---- z0 = min(V@F^T, Bb), y0 = 0 ----
    mgemm<M_ZI><<<dim3(16, 13), 256, 0, stream>>>(Vh, Vl, 416, Fsh, Fsl, 416, 13,
        zAh, zAl, 832, NSo, NSo, yv, Bb, NV, NV, nullptr, flag);

    // ---- ADMM loop ----
    short *zch = zAh, *zcl = zAl, *znh = zBh, *znl = zBl;
    for (int it = 0; it < 40; it++) {
        admm_mfma<<<dim3(16, 13), 256, 0, stream>>>(zch, zcl, Gh, Gl, C2, yv, Bb, znh, znl);
        short* t;
        t = zch; zch = znh; znh = t;
        t = zcl; zcl = znl; znl = t;
    }

    // ---- U1 = zy@FK; out = (2V@Kinv + U1)^T ----
    mgemm<M_U1><<<dim3(16, 7), 256, 0, stream>>>(zch, zcl, 832, FTh, FTl, 800, 25,
        NSo, NSo, 0, NSo, NSo, U1, NF, NV, NV, nullptr, flag);
    mgemm<M_FIN><<<dim3(16, 7), 256, 0, stream>>>(Vh, Vl, 416, Xch, Xcl, 416, 13,
        NSo, NSo, 0, NSo, NSo, NFo, U1, NV, NV, d_out, flag);
}

// Round 6
// 1151.106 us; speedup vs baseline: 1.9741x; 1.9741x over previous
//
#include <hip/hip_runtime.h>
#include <hip/hip_bf16.h>
#include <math.h>

typedef __hip_bfloat16 bf16;
typedef __attribute__((ext_vector_type(8))) short short8;
typedef __attribute__((ext_vector_type(4))) float f32x4;

// ---------- epilogue ids ----------
enum {
    M_H2 = 0,   // relu(acc + bias[gn]) -> split (sO)
    M_V,        // tanh(acc + bias[gn]) * ub[gn&7] -> split (Nreal 400, pad 416)
    M_KM,       // acc + 2*(m==n) -> split + fp32 Km[400x400]
    M_W,        // acc -> split
    M_NS,       // 2*Xf - acc -> split + fp32 Xf'
    M_FK,       // acc -> split + transposed split
    M_G,        // acc -> split (832)
    M_C2,       // 2*acc -> fp32 (gn<800)
    M_ZI,       // w0 = min(acc - Bb, 0) -> split (832); y=0 -> fp32
    M_U1,       // acc -> fp32 U1 (gn<400)
    M_FIN,      // 2*acc + U1 -> out[gn*1024+gm] (gn<400), dtype per flag
    M_BBS,      // acc + g[gn] -> fp32 Bb + split (832) (gn<800)
    M_Q,        // acc + C2 - Bb -> fp32 Q (gn<800)
};

__device__ __forceinline__ float ldf(const void* p, long i, int f32) {
    return f32 ? ((const float*)p)[i]
               : __bfloat162float(((const bf16*)p)[i]);
}
__device__ __forceinline__ void split_bf16(float z, short& hi, short& lo) {
    bf16 h = __float2bfloat16(z);
    hi = *reinterpret_cast<short*>(&h);
    bf16 l = __float2bfloat16(z - __bfloat162float(h));
    lo = *reinterpret_cast<short*>(&l);
}
__device__ __forceinline__ void sstore(short* H, short* L, long o, float v) {
    short h, l; split_bf16(v, h, l); H[o] = h; L[o] = l;
}

// ---------- dtype detect (+ zero the rowmax scalar) ----------
__global__ void detect_kernel(const void* Fp, int* flag, int* sc) {
    __shared__ int hit;
    if (threadIdx.x == 0) { hit = 0; sc[0] = 0; }
    __syncthreads();
    const unsigned short* u = (const unsigned short*)Fp;
    int local = 0;
    for (int i = threadIdx.x; i < 16384; i += 256) {
        int e = (u[i] >> 7) & 0xFF;
        if (e >= 0x90) local = 1;
    }
    if (local) atomicOr(&hit, 1);
    __syncthreads();
    if (threadIdx.x == 0) flag[0] = hit;
}

// ---------- fused input prep: transpose/pad + split everything ----------
__global__ __launch_bounds__(256)
void prep_kernel(const void* __restrict__ F, const void* __restrict__ W2,
                 const void* __restrict__ W3, const void* __restrict__ X0,
                 const void* __restrict__ W1, const void* __restrict__ H0,
                 short* __restrict__ Fth, short* __restrict__ Ftl,
                 short* __restrict__ Fsh, short* __restrict__ Fsl,
                 short* __restrict__ W2h, short* __restrict__ W2l,
                 short* __restrict__ W3h, short* __restrict__ W3l,
                 short* __restrict__ X0h, short* __restrict__ X0l,
                 short* __restrict__ W1h, short* __restrict__ W1l,
                 short* __restrict__ H0h, short* __restrict__ H0l,
                 const int* __restrict__ flag)
{
    const int f32 = flag[0];
    int idx = blockIdx.x * 256 + threadIdx.x;
    if (idx < 320000) {                       // F [800x400]
        int i = idx / 400, j = idx % 400;
        float v = ldf(F, idx, f32);
        sstore(Fth, Ftl, (long)j * 800 + i, v);
        sstore(Fsh, Fsl, (long)i * 416 + j, v);
        return;
    }
    idx -= 320000;
    if (idx < 262144) {                       // W2 [512x512] -> W2t[n*512+k]
        int k = idx >> 9, n = idx & 511;
        sstore(W2h, W2l, (long)n * 512 + k, ldf(W2, idx, f32));
        return;
    }
    idx -= 262144;
    if (idx < 204800) {                       // W3 [512x400] -> W3t[n*512+k]
        int k = idx / 400, n = idx % 400;
        sstore(W3h, W3l, (long)n * 512 + k, ldf(W3, idx, f32));
        return;
    }
    idx -= 204800;
    if (idx < 32768) {                        // X0 [32x1024] -> X0t[b*32+k]
        int k = idx >> 10, b = idx & 1023;
        sstore(X0h, X0l, (long)b * 32 + k, ldf(X0, idx, f32));
        return;
    }
    idx -= 32768;
    if (idx < 16384) {                        // W1 [32x512] -> W1t[n*32+k]
        int k = idx >> 9, n = idx & 511;
        sstore(W1h, W1l, (long)n * 32 + k, ldf(W1, idx, f32));
        return;
    }
    idx -= 16384;
    if (idx < 25600) {                        // H0 [800x32] copy-split
        sstore(H0h, H0l, idx, ldf(H0, idx, f32));
    }
}

// ---------- generic split-3 MFMA GEMM, 64x64 tile, BK=32, reg-prefetch ----------
template<int EPI>
__global__ __launch_bounds__(256)
void mgemm(const short* __restrict__ Ah, const short* __restrict__ Al, int sA,
           const short* __restrict__ Bth, const short* __restrict__ Btl, int sB,
           int KC,
           short* __restrict__ Oh, short* __restrict__ Ol, int sO,
           short* __restrict__ Oth, short* __restrict__ Otl,
           float* __restrict__ fout, const float* __restrict__ faux,
           const float* __restrict__ faux2,
           const void* __restrict__ bias, const void* __restrict__ ubp,
           void* __restrict__ rawout, const int* __restrict__ flag)
{
    __shared__ __align__(16) short Ahs[64][32];
    __shared__ __align__(16) short Als[64][32];
    __shared__ __align__(16) short Bhs[64][32];
    __shared__ __align__(16) short Bls[64][32];

    const int tid = threadIdx.x;
    const int m0 = blockIdx.x * 64, n0 = blockIdx.y * 64;
    const int wave = tid >> 6, lane = tid & 63;
    const int wm = (wave & 1) * 32, wn = (wave >> 1) * 32;
    const int q = lane >> 4, r = lane & 15;
    const int sm = tid >> 2, sk = (tid & 3) * 8;

    f32x4 acc[2][2];
#pragma unroll
    for (int t = 0; t < 2; t++)
#pragma unroll
        for (int u = 0; u < 2; u++)
#pragma unroll
            for (int i = 0; i < 4; i++) acc[t][u][i] = 0.f;

    const long arow = (long)(m0 + sm) * sA + sk;
    const long brow = (long)(n0 + sm) * sB + sk;

    uint4 pAh = *(const uint4*)&Ah[arow];
    uint4 pAl = *(const uint4*)&Al[arow];
    uint4 pBh = *(const uint4*)&Bth[brow];
    uint4 pBl = *(const uint4*)&Btl[brow];

    for (int c = 0; c < KC; c++) {
        __syncthreads();
        *(uint4*)&Ahs[sm][sk] = pAh;
        *(uint4*)&Als[sm][sk] = pAl;
        *(uint4*)&Bhs[sm][sk] = pBh;
        *(uint4*)&Bls[sm][sk] = pBl;
        if (c + 1 < KC) {
            int k0 = (c + 1) * 32;
            pAh = *(const uint4*)&Ah[arow + k0];
            pAl = *(const uint4*)&Al[arow + k0];
            pBh = *(const uint4*)&Bth[brow + k0];
            pBl = *(const uint4*)&Btl[brow + k0];
        }
        __syncthreads();

        short8 a_h[2], a_l[2], b_h[2], b_l[2];
#pragma unroll
        for (int t = 0; t < 2; t++) {
            a_h[t] = *(const short8*)&Ahs[wm + t * 16 + r][q * 8];
            a_l[t] = *(const short8*)&Als[wm + t * 16 + r][q * 8];
        }
#pragma unroll
        for (int u = 0; u < 2; u++) {
            b_h[u] = *(const short8*)&Bhs[wn + u * 16 + r][q * 8];
            b_l[u] = *(const short8*)&Bls[wn + u * 16 + r][q * 8];
        }
#pragma unroll
        for (int t = 0; t < 2; t++)
#pragma unroll
            for (int u = 0; u < 2; u++) {
                acc[t][u] = __builtin_amdgcn_mfma_f32_16x16x32_bf16(a_h[t], b_h[u], acc[t][u], 0, 0, 0);
                acc[t][u] = __builtin_amdgcn_mfma_f32_16x16x32_bf16(a_h[t], b_l[u], acc[t][u], 0, 0, 0);
                acc[t][u] = __builtin_amdgcn_mfma_f32_16x16x32_bf16(a_l[t], b_h[u], acc[t][u], 0, 0, 0);
            }
    }

    const int f32 = flag[0];
    // C/D layout: col = lane&15 (gn), row = quad*4 + reg (gm)
#pragma unroll
    for (int t = 0; t < 2; t++) {
#pragma unroll
        for (int u = 0; u < 2; u++) {
            int gn = n0 + wn + u * 16 + r;
#pragma unroll
            for (int i = 0; i < 4; i++) {
                int gm = m0 + wm + t * 16 + q * 4 + i;
                float v = acc[t][u][i];
                if constexpr (EPI == M_H2) {
                    float val = fmaxf(v + ldf(bias, gn, f32), 0.f);
                    sstore(Oh, Ol, (long)gm * sO + gn, val);
                } else if constexpr (EPI == M_V) {
                    if (gn < 416) {
                        float val = 0.f;
                        if (gn < 400)
                            val = tanhf(v + ldf(bias, gn, f32)) * ldf(ubp, gn & 7, f32);
                        sstore(Oh, Ol, (long)gm * sO + gn, val);
                    }
                } else if constexpr (EPI == M_KM) {
                    if (gn < 416) {
                        float val = 0.f;
                        if (gm < 400 && gn < 400) {
                            val = v + ((gm == gn) ? 2.f : 0.f);
                            fout[gm * 400 + gn] = val;
                        }
                        sstore(Oh, Ol, (long)gm * sO + gn, val);
                    }
                } else if constexpr (EPI == M_W) {
                    if (gn < 416) sstore(Oh, Ol, (long)gm * sO + gn, v);
                } else if constexpr (EPI == M_NS) {
                    if (gn < 416) {
                        float val = 0.f;
                        if (gm < 400 && gn < 400) {
                            val = 2.f * faux[gm * 400 + gn] - v;
                            fout[gm * 400 + gn] = val;
                        }
                        sstore(Oh, Ol, (long)gm * sO + gn, val);
                    }
                } else if constexpr (EPI == M_FK) {
                    if (gn < 416) sstore(Oh, Ol, (long)gm * sO + gn, v);
                    if (gm < 800) sstore(Oth, Otl, (long)gn * 800 + gm, v);
                } else if constexpr (EPI == M_G) {
                    sstore(Oh, Ol, (long)gm * sO + gn, v);
                } else if constexpr (EPI == M_C2) {
                    if (gn < 800) fout[(long)gm * 800 + gn] = 2.f * v;
                } else if constexpr (EPI == M_ZI) {
                    if (gn < 800) {
                        long o8 = (long)gm * 800 + gn;
                        float w0 = fminf(v - faux[o8], 0.f);   // faux = Bb
                        fout[o8] = 0.f;                        // y = 0
                        sstore(Oh, Ol, (long)gm * 832 + gn, w0);
                    }
                } else if constexpr (EPI == M_U1) {
                    if (gn < 400) fout[(long)gm * 400 + gn] = v;
                } else if constexpr (EPI == M_FIN) {
                    if (gn < 400) {
                        float val = 2.f * v + faux[(long)gm * 400 + gn];
                        long oo = (long)gn * 1024 + gm;
                        if (f32) ((float*)rawout)[oo] = val;
                        else     ((bf16*)rawout)[oo] = __float2bfloat16(val);
                    }
                } else if constexpr (EPI == M_BBS) {
                    if (gn < 800) {
                        float val = v + ldf(bias, gn, f32);     // bias = g
                        fout[(long)gm * 800 + gn] = val;
                        sstore(Oh, Ol, (long)gm * 832 + gn, val);
                    }
                } else if constexpr (EPI == M_Q) {
                    if (gn < 800) {
                        long o8 = (long)gm * 800 + gn;
                        fout[o8] = v + faux[o8] - faux2[o8];   // Bb@G + C2 - Bb
                    }
                }
            }
        }
    }
}

// ---------- ADMM iteration: 16x64 tile, 832 blocks, true LDS double-buffer ----------
// d = w@G + Q + y;  y' = max(d,0);  w' = -|d|   (LAST: store zy = Bb - |d| instead)
template<bool LAST>
__global__ __launch_bounds__(256)
void admm2(const short* __restrict__ wh, const short* __restrict__ wl,
           const short* __restrict__ Gh_, const short* __restrict__ Gl_,
           const float* __restrict__ Q, float* __restrict__ yv,
           const float* __restrict__ Bb,
           short* __restrict__ wh_o, short* __restrict__ wl_o)
{
    __shared__ __align__(16) short Ahs[2][16][32];
    __shared__ __align__(16) short Als[2][16][32];
    __shared__ __align__(16) short Bhs[2][64][32];
    __shared__ __align__(16) short Bls[2][64][32];

    const int tid = threadIdx.x;
    const int m0 = blockIdx.x * 16, n0 = blockIdx.y * 64;
    const int wave = tid >> 6, lane = tid & 63;
    const int q = lane >> 4, r = lane & 15;
    const int brow = tid >> 2, bcol = (tid & 3) * 8;
    const int arow = (tid & 63) >> 2, acol = (tid & 3) * 8;
    const bool stA_h = (tid < 64);
    const bool stA_l = (tid >= 64 && tid < 128);

    const long gB = (long)(n0 + brow) * 832 + bcol;
    const long gA = (long)(m0 + arow) * 832 + acol;

    f32x4 acc = {0.f, 0.f, 0.f, 0.f};

    // prologue: stage chunk 0 into buffer 0
    {
        uint4 b0 = *(const uint4*)&Gh_[gB];
        uint4 b1 = *(const uint4*)&Gl_[gB];
        *(uint4*)&Bhs[0][brow][bcol] = b0;
        *(uint4*)&Bls[0][brow][bcol] = b1;
        if (stA_h) *(uint4*)&Ahs[0][arow][acol] = *(const uint4*)&wh[gA];
        if (stA_l) *(uint4*)&Als[0][arow][acol] = *(const uint4*)&wl[gA];
    }

    for (int c = 0; c < 25; c++) {
        uint4 nb0 = {}, nb1 = {}, na = {};
        if (c < 24) {
            long kb = gB + (long)(c + 1) * 32;
            nb0 = *(const uint4*)&Gh_[kb];
            nb1 = *(const uint4*)&Gl_[kb];
            if (stA_h) na = *(const uint4*)&wh[gA + (long)(c + 1) * 32];
            if (stA_l) na = *(const uint4*)&wl[gA + (long)(c + 1) * 32];
        }
        __syncthreads();
        const int cb = c & 1;
        short8 af_h = *(const short8*)&Ahs[cb][r][q * 8];
        short8 af_l = *(const short8*)&Als[cb][r][q * 8];
        short8 bf_h = *(const short8*)&Bhs[cb][wave * 16 + r][q * 8];
        short8 bf_l = *(const short8*)&Bls[cb][wave * 16 + r][q * 8];
        acc = __builtin_amdgcn_mfma_f32_16x16x32_bf16(af_h, bf_h, acc, 0, 0, 0);
        acc = __builtin_amdgcn_mfma_f32_16x16x32_bf16(af_h, bf_l, acc, 0, 0, 0);
        acc = __builtin_amdgcn_mfma_f32_16x16x32_bf16(af_l, bf_h, acc, 0, 0, 0);
        if (c < 24) {
            const int nb = cb ^ 1;
            *(uint4*)&Bhs[nb][brow][bcol] = nb0;
            *(uint4*)&Bls[nb][brow][bcol] = nb1;
            if (stA_h) *(uint4*)&Ahs[nb][arow][acol] = na;
            if (stA_l) *(uint4*)&Als[nb][arow][acol] = na;
        }
    }

    // epilogue: C/D col = lane&15, row = q*4+i
    int gn = n0 + wave * 16 + r;
    if (gn < 800) {
#pragma unroll
        for (int i = 0; i < 4; i++) {
            int gm = m0 + q * 4 + i;
            long o = (long)gm * 800 + gn;
            float d = acc[i] + Q[o] + yv[o];
            if constexpr (LAST) {
                sstore(wh_o, wl_o, (long)gm * 832 + gn, Bb[o] - fabsf(d));
            } else {
                yv[o] = fmaxf(d, 0.f);
                sstore(wh_o, wl_o, (long)gm * 832 + gn, -fabsf(d));
            }
        }
    }
}

// ---------- Gershgorin bound ----------
__global__ __launch_bounds__(256)
void rowinf_kernel(const float* __restrict__ Km, int* __restrict__ s)
{
    int row = blockIdx.x * 4 + (threadIdx.x >> 6);
    int lane = threadIdx.x & 63;
    float sum = 0.f;
    for (int j = lane; j < 400; j += 64) sum += fabsf(Km[row * 400 + j]);
#pragma unroll
    for (int off = 32; off > 0; off >>= 1) sum += __shfl_down(sum, off, 64);
    if (lane == 0) atomicMax(s, __float_as_int(sum));
}

// X = t*I (fp32 + split), t = 2/(2 + S); valid since eig(K) in [2, S]
__global__ __launch_bounds__(256)
void xinit_kernel(float* __restrict__ Xf, short* __restrict__ Xh, short* __restrict__ Xl,
                  const int* __restrict__ s)
{
    int idx = blockIdx.x * 256 + threadIdx.x;
    if (idx >= 400 * 400) return;
    int i = idx / 400, j = idx % 400;
    float S = __int_as_float(s[0]);
    float t = 2.f / (2.f + S);
    float v = (i == j) ? t : 0.f;
    Xf[idx] = v;
    sstore(Xh, Xl, (long)i * 416 + j, v);
}

extern "C" void kernel_launch(void* const* d_in, const int* in_sizes, int n_in,
                              void* d_out, int out_size, void* d_ws, size_t ws_size,
                              hipStream_t stream)
{
    const void* X0 = d_in[0];
    const void* W1 = d_in[1];
    const void* b1 = d_in[2];
    const void* W2 = d_in[3];
    const void* b2 = d_in[4];
    const void* W3 = d_in[5];
    const void* b3 = d_in[6];
    const void* ub = d_in[7];
    const void* F  = d_in[8];
    const void* g  = d_in[9];
    const void* H0 = d_in[10];
    (void)in_sizes; (void)n_in; (void)out_size; (void)ws_size;

    char* w = (char*)d_ws;
    size_t off = 0;
    auto allocb = [&](size_t bytes) { char* p = w + off; off += (bytes + 15) & ~size_t(15); return p; };

    // fp32 region
    float* Km  = (float*)allocb(400 * 400 * 4);
    float* XfA = (float*)allocb(400 * 400 * 4);
    float* XfB = (float*)allocb(400 * 400 * 4);
    float* Bb  = (float*)allocb(1024 * 800 * 4);
    float* C2  = (float*)allocb(1024 * 800 * 4);
    float* Qf  = (float*)allocb(1024 * 800 * 4);
    float* yv  = (float*)allocb(1024 * 800 * 4);
    float* U1  = (float*)allocb(1024 * 400 * 4);
    int*   sc  = (int*)allocb(64);
    int*  flag = (int*)allocb(64);

    // split region (memset once per call -> zero rims)
    char* split_base = w + off;
    auto allocs = [&](size_t n) { return (short*)allocb(n * 2); };
    short *W1t_h = allocs(512*32),  *W1t_l = allocs(512*32);
    short *W2t_h = allocs(512*512), *W2t_l = allocs(512*512);
    short *W3t_h = allocs(448*512), *W3t_l = allocs(448*512);
    short *X0t_h = allocs(1024*32), *X0t_l = allocs(1024*32);
    short *H0s_h = allocs(832*32),  *H0s_l = allocs(832*32);
    short *H1h = allocs(1024*512),  *H1l = allocs(1024*512);
    short *H2h = allocs(1024*512),  *H2l = allocs(1024*512);
    short *Vh  = allocs(1024*416),  *Vl  = allocs(1024*416);
    short *Fsh = allocs(832*416),   *Fsl = allocs(832*416);
    short *Fth = allocs(448*800),   *Ftl = allocs(448*800);
    short *Kmh = allocs(448*416),   *Kml = allocs(448*416);
    short *XAh = allocs(448*416),   *XAl = allocs(448*416);
    short *XBh = allocs(448*416),   *XBl = allocs(448*416);
    short *Wsh = allocs(448*416),   *Wsl = allocs(448*416);
    short *FKh = allocs(832*416),   *FKl = allocs(832*416);
    short *FTh = allocs(448*800),   *FTl = allocs(448*800);
    short *Gh  = allocs(832*832),   *Gl  = allocs(832*832);
    short *Bbs_h = allocs(1024*832), *Bbs_l = allocs(1024*832);
    short *zAh = allocs(1024*832),  *zAl = allocs(1024*832);
    short *zBh = allocs(1024*832),  *zBl = allocs(1024*832);
    size_t split_bytes = (size_t)((w + off) - split_base);

    short* NSo = nullptr;
    float* NFo = nullptr;
    const float* NF = nullptr;
    const void* NV = nullptr;

    // ---- detect dtype, zero rims, prep all operands ----
    detect_kernel<<<1, 256, 0, stream>>>(F, flag, sc);
    hipMemsetAsync(split_base, 0, split_bytes, stream);
    prep_kernel<<<(861696 + 255) / 256, 256, 0, stream>>>(
        F, W2, W3, X0, W1, H0,
        Fth, Ftl, Fsh, Fsl, W2t_h, W2t_l, W3t_h, W3t_l,
        X0t_h, X0t_l, W1t_h, W1t_l, H0s_h, H0s_l, flag);

    // ---- MLP head ----
    mgemm<M_H2><<<dim3(16, 8), 256, 0, stream>>>(X0t_h, X0t_l, 32, W1t_h, W1t_l, 32, 1,
        H1h, H1l, 512, NSo, NSo, NFo, NF, NF, b1, NV, nullptr, flag);
    mgemm<M_H2><<<dim3(16, 8), 256, 0, stream>>>(H1h, H1l, 512, W2t_h, W2t_l, 512, 16,
        H2h, H2l, 512, NSo, NSo, NFo, NF, NF, b2, NV, nullptr, flag);
    mgemm<M_V><<<dim3(16, 7), 256, 0, stream>>>(H2h, H2l, 512, W3t_h, W3t_l, 512, 16,
        Vh, Vl, 416, NSo, NSo, NFo, NF, NF, b3, ub, nullptr, flag);

    // ---- Bb = g + X0^T H0^T (fp32 + split) ----
    mgemm<M_BBS><<<dim3(16, 13), 256, 0, stream>>>(X0t_h, X0t_l, 32, H0s_h, H0s_l, 32, 1,
        Bbs_h, Bbs_l, 832, NSo, NSo, Bb, NF, NF, g, NV, nullptr, flag);

    // ---- Km = 2I + F^T F ----
    mgemm<M_KM><<<dim3(7, 7), 256, 0, stream>>>(Fth, Ftl, 800, Fth, Ftl, 800, 25,
        Kmh, Kml, 416, NSo, NSo, Km, NF, NF, NV, NV, nullptr, flag);

    // ---- Kinv via Newton-Schulz, 8 iters; Gershgorin init ----
    rowinf_kernel<<<100, 256, 0, stream>>>(Km, sc);
    xinit_kernel<<<625, 256, 0, stream>>>(XfA, XAh, XAl, sc);
    short *Xch = XAh, *Xcl = XAl, *Xnh = XBh, *Xnl = XBl;
    float *Xfc = XfA, *Xfn = XfB;
    for (int it = 0; it < 8; it++) {
        mgemm<M_W><<<dim3(7, 7), 256, 0, stream>>>(Xch, Xcl, 416, Kmh, Kml, 416, 13,
            Wsh, Wsl, 416, NSo, NSo, NFo, NF, NF, NV, NV, nullptr, flag);
        mgemm<M_NS><<<dim3(7, 7), 256, 0, stream>>>(Wsh, Wsl, 416, Xch, Xcl, 416, 13,
            Xnh, Xnl, 416, NSo, NSo, Xfn, Xfc, NF, NV, NV, nullptr, flag);
        short* t;
        t = Xch; Xch = Xnh; Xnh = t;
        t = Xcl; Xcl = Xnl; Xnl = t;
        float* tf = Xfc; Xfc = Xfn; Xfn = tf;
    }
    // (Xch,Xcl) == Kinv split (symmetric)

    // ---- FK = F@Kinv (+FK^T), C2 = 2V@FK^T, G = FK@F^T ----
    mgemm<M_FK><<<dim3(13, 7), 256, 0, stream>>>(Fsh, Fsl, 416, Xch, Xcl, 416, 13,
        FKh, FKl, 416, FTh, FTl, NFo, NF, NF, NV, NV, nullptr, flag);
    mgemm<M_C2><<<dim3(16, 13), 256, 0, stream>>>(Vh, Vl, 416, FKh, FKl, 416, 13,
        NSo, NSo, 0, NSo, NSo, C2, NF, NF, NV, NV, nullptr, flag);
    mgemm<M_G><<<dim3(13, 13), 256, 0, stream>>>(FKh, FKl, 416, Fsh, Fsl, 416, 13,
        Gh, Gl, 832, NSo, NSo, NFo, NF, NF, NV, NV, nullptr, flag);

    // ---- Q = Bb@G + C2 - Bb ----
    mgemm<M_Q><<<dim3(16, 13), 256, 0, stream>>>(Bbs_h, Bbs_l, 832, Gh, Gl, 832, 25,
        NSo, NSo, 0, NSo, NSo, Qf, C2, Bb, NV, NV, nullptr, flag);

    // ---- w0 = min(V@F^T - Bb, 0), y0 = 0 ----
    mgemm<M_ZI><<<dim3(16, 13), 256, 0, stream>>>(Vh, Vl, 416, Fsh, Fsl, 416, 13,
        zAh, zAl, 832, NSo, NSo, yv, Bb, NF, NV, NV, nullptr, flag);

    // ---- ADMM loop: d = w@G + Q + y; y' = max(d,0); w' = -|d|; last: zy = Bb - |d| ----
    short *zch = zAh, *zcl = zAl, *znh = zBh, *znl = zBl;
    for (int it = 0; it < 40; it++) {
        if (it == 39)
            admm2<true><<<dim3(64, 13), 256, 0, stream>>>(zch, zcl, Gh, Gl, Qf, yv, Bb, znh, znl);
        else
            admm2<false><<<dim3(64, 13), 256, 0, stream>>>(zch, zcl, Gh, Gl, Qf, yv, Bb, znh, znl);
        short* t;
        t = zch; zch = znh; znh = t;
        t = zcl; zcl = znl; znl = t;
    }
    // zch/zcl = final zy split (stride 832)

    // ---- U1 = zy@FK; out = (2V@Kinv + U1)^T ----
    mgemm<M_U1><<<dim3(16, 7), 256, 0, stream>>>(zch, zcl, 832, FTh, FTl, 800, 25,
        NSo, NSo, 0, NSo, NSo, U1, NF, NF, NV, NV, nullptr, flag);
    mgemm<M_FIN><<<dim3(16, 7), 256, 0, stream>>>(Vh, Vl, 416, Xch, Xcl, 416, 13,
        NSo, NSo, 0, NSo, NSo, NFo, U1, NF, NV, NV, d_out, flag);
}